// Round 13
// baseline (673.601 us; speedup 1.0000x reference)
//
#include <hip/hip_runtime.h>
#include <math.h>

#define NN 100000
#define EE 1600000
#define BB 64
#define FF 16
#define HH 128
#define GG 8
#define K0 19
#define BN_EPS 1e-5f
#define PCH 16
#define BSHIFT 8
#define BNODES 256
#define NBINS 391          // ceil(NN/256)
#define BCAP 8192
#define ACH 2048           // edges per phase-A block

typedef short bf16x8 __attribute__((ext_vector_type(8)));
typedef float f32x4 __attribute__((ext_vector_type(4)));

__device__ __forceinline__ float elu01f(float v) {
    return v > 0.f ? v : 0.1f * (__expf(v) - 1.f);
}

__device__ __forceinline__ unsigned f2bfu(float f) {
    unsigned u = __float_as_uint(f);
    unsigned r = u + 0x7FFFu + ((u >> 16) & 1u);
    return r >> 16;
}
__device__ __forceinline__ short f2bf(float f) { return (short)f2bfu(f); }
__device__ __forceinline__ float bfu2f(unsigned short b) {
    return __uint_as_float(((unsigned)b) << 16);
}
__device__ __forceinline__ float bflo(unsigned u) { return __uint_as_float(u << 16); }
__device__ __forceinline__ float bfhi(unsigned u) { return __uint_as_float(u & 0xffff0000u); }

// ---------------- CSR build: 2-phase LDS counting sort ----------------
__global__ __launch_bounds__(256) void k_binA(const int* __restrict__ esrc, const int* __restrict__ edst,
                                              int* __restrict__ bincnt, uint2* __restrict__ binbuf) {
    __shared__ int hist[NBINS];
    __shared__ int gbase[NBINS];
    __shared__ int cur[NBINS];
    __shared__ int sc[512];
    __shared__ uint2 ebuf[ACH];
    __shared__ uint2 sorted[ACH];
    int tid = threadIdx.x;
    int e0 = blockIdx.x * ACH;
    int n = min(ACH, EE - e0);
    for (int i = tid; i < NBINS; i += 256) hist[i] = 0;
    __syncthreads();
    for (int i = tid; i < n; i += 256) {
        int s = esrc[e0 + i];
        int d = edst[e0 + i];
        ebuf[i] = make_uint2((unsigned)s, (unsigned)d);
        atomicAdd(&hist[d >> BSHIFT], 1);
    }
    __syncthreads();
    sc[tid] = (tid < NBINS) ? hist[tid] : 0;
    sc[tid + 256] = (tid + 256 < NBINS) ? hist[tid + 256] : 0;
    __syncthreads();
    for (int off = 1; off < 512; off <<= 1) {
        int a0 = sc[tid], a1 = sc[tid + 256];
        int b0 = (tid >= off) ? sc[tid - off] : 0;
        int b1 = (tid + 256 >= off) ? sc[tid + 256 - off] : 0;
        __syncthreads();
        sc[tid] = a0 + b0;
        sc[tid + 256] = a1 + b1;
        __syncthreads();
    }
    for (int b = tid; b < NBINS; b += 256) {
        int c = hist[b];
        gbase[b] = (c > 0) ? atomicAdd(&bincnt[b], c) : 0;
        cur[b] = (b > 0) ? sc[b - 1] : 0;
    }
    __syncthreads();
    for (int i = tid; i < n; i += 256) {
        uint2 e = ebuf[i];
        int b = (int)(e.y >> BSHIFT);
        int pos = atomicAdd(&cur[b], 1);
        sorted[pos] = e;
    }
    __syncthreads();
    for (int i = tid; i < n; i += 256) {
        uint2 e = sorted[i];
        int b = (int)(e.y >> BSHIFT);
        int ls = (b > 0) ? sc[b - 1] : 0;
        int gpos = gbase[b] + (i - ls);
        binbuf[(size_t)b * BCAP + gpos] = e;
    }
}

// binscan + gptr fused
__global__ void k_binscan(const int* __restrict__ bincnt, int* __restrict__ binstart, int* __restrict__ rp,
                          const int* __restrict__ batch, int* __restrict__ gptr) {
    __shared__ int sc[512];
    int t = threadIdx.x;
    sc[t] = (t < NBINS) ? bincnt[t] : 0;
    __syncthreads();
    for (int off = 1; off < 512; off <<= 1) {
        int v = (t >= off) ? sc[t - off] : 0;
        __syncthreads();
        sc[t] += v;
        __syncthreads();
    }
    if (t < NBINS) binstart[t] = (t > 0) ? sc[t - 1] : 0;
    if (t == 0) rp[NN] = EE;
    if (t <= BB) {
        int lo = 0, hi = NN;
        while (lo < hi) { int mid = (lo + hi) >> 1; if (batch[mid] < t) lo = mid + 1; else hi = mid; }
        gptr[t] = lo;
    }
}

__global__ __launch_bounds__(256) void k_binB(const uint2* __restrict__ binbuf, const int* __restrict__ bincnt,
                                              const int* __restrict__ binstart,
                                              int* __restrict__ rp, int* __restrict__ srcs) {
    __shared__ int hist[BNODES];
    __shared__ int scx[BNODES];
    __shared__ int scur[BNODES];
    __shared__ int sbuf[BCAP];
    int b = blockIdx.x;
    int n = bincnt[b];
    int tid = threadIdx.x;
    hist[tid] = 0;
    __syncthreads();
    const uint2* eb = binbuf + (size_t)b * BCAP;
    for (int i = tid; i < n; i += 256)
        atomicAdd(&hist[eb[i].y & (BNODES - 1)], 1);
    __syncthreads();
    scx[tid] = hist[tid];
    __syncthreads();
    for (int off = 1; off < 256; off <<= 1) {
        int v = (tid >= off) ? scx[tid - off] : 0;
        __syncthreads();
        scx[tid] += v;
        __syncthreads();
    }
    int base = binstart[b];
    int excl = (tid > 0) ? scx[tid - 1] : 0;
    int node = (b << BSHIFT) + tid;
    if (node < NN) rp[node] = base + excl;
    scur[tid] = excl;
    __syncthreads();
    for (int i = tid; i < n; i += 256) {
        uint2 e = eb[i];
        int pos = atomicAdd(&scur[e.y & (BNODES - 1)], 1);
        sbuf[pos] = (int)e.x;
    }
    __syncthreads();
    for (int i = tid; i < n; i += 256) srcs[base + i] = sbuf[i];
}

// ---------------- weight prep: fp32 [k][col] -> bf16 transposed [col][k] ----------------
__global__ __launch_bounds__(256) void k_wprep(const float* __restrict__ w2_0, const float* __restrict__ w1_r,
                                               const float* __restrict__ w2_r, short* __restrict__ wt) {
    int t = blockIdx.x * 256 + threadIdx.x;
    if (t >= 5 * HH * HH) return;
    int m = t >> 14;
    int rem = t & 16383;
    int col = rem >> 7;
    int k = rem & 127;
    const float* src = (m == 0) ? w2_0 : (m <= 2 ? w1_r + (size_t)(m - 1) * HH * HH
                                                 : w2_r + (size_t)(m - 3) * HH * HH);
    wt[t] = f2bf(src[k * HH + col]);
}

// ---------------- feature build (bf16, rows padded to 32 ch = 64B) ----------------
__global__ __launch_bounds__(256) void k_buildx0(const float* __restrict__ h0, const float* __restrict__ coord,
                                                 unsigned short* __restrict__ x0) {
    int i = blockIdx.x * 256 + threadIdx.x;
    if (i >= NN * 32) return;
    int node = i >> 5, k = i & 31;
    float v = 0.f;
    if (k < FF) v = h0[node * FF + k];
    else if (k < K0) v = coord[node * 3 + (k - FF)];
    x0[i] = (unsigned short)f2bfu(v);
}

// ---------------- layer-0 aggregation: 16 edges/wave (4 lanes x 16B per row) ----------------
__global__ __launch_bounds__(256) void k_agg_small(const uint4* __restrict__ x, const int* __restrict__ rp,
                                                   const int* __restrict__ srcs, uint4* __restrict__ y) {
    int w = (blockIdx.x * 256 + threadIdx.x) >> 6;
    int lane = threadIdx.x & 63;
    if (w >= NN) return;
    int e = lane >> 2, q = lane & 3;
    int beg = rp[w], end = rp[w + 1];
    float acc[8];
    {
        if (e == 0) {
            uint4 u = x[(size_t)w * 4 + q];
            acc[0] = bflo(u.x); acc[1] = bfhi(u.x);
            acc[2] = bflo(u.y); acc[3] = bfhi(u.y);
            acc[4] = bflo(u.z); acc[5] = bfhi(u.z);
            acc[6] = bflo(u.w); acc[7] = bfhi(u.w);
        } else {
            #pragma unroll
            for (int j = 0; j < 8; j++) acc[j] = 0.f;
        }
    }
    for (int p = beg; p < end; p += 16) {
        int rem = end - p;
        bool act = e < rem;
        int sn = act ? srcs[p + e] : 0;
        uint4 u = x[(size_t)sn * 4 + q];
        float m = act ? 1.f : 0.f;
        acc[0] = fmaf(m, bflo(u.x), acc[0]); acc[1] = fmaf(m, bfhi(u.x), acc[1]);
        acc[2] = fmaf(m, bflo(u.y), acc[2]); acc[3] = fmaf(m, bfhi(u.y), acc[3]);
        acc[4] = fmaf(m, bflo(u.z), acc[4]); acc[5] = fmaf(m, bfhi(u.z), acc[5]);
        acc[6] = fmaf(m, bflo(u.w), acc[6]); acc[7] = fmaf(m, bfhi(u.w), acc[7]);
    }
    #pragma unroll
    for (int mask = 4; mask <= 32; mask <<= 1)
        #pragma unroll
        for (int j = 0; j < 8; j++)
            acc[j] += __shfl_xor(acc[j], mask, 64);
    if (e == 0) {
        uint4 o;
        o.x = f2bfu(acc[0]) | (f2bfu(acc[1]) << 16);
        o.y = f2bfu(acc[2]) | (f2bfu(acc[3]) << 16);
        o.z = f2bfu(acc[4]) | (f2bfu(acc[5]) << 16);
        o.w = f2bfu(acc[6]) | (f2bfu(acc[7]) << 16);
        y[(size_t)w * 4 + q] = o;
    }
}

// ---------------- FUSED: bf16 gather-aggregate + MFMA GEMM1 (+stats) ----------------
// block = 64 rows; wave gathers 16 rows into LDS A-tile (same math/rounding as
// standalone agg128_bf -> ybf -> gemm path), then MFMA phase as usual.
__global__ __launch_bounds__(256) void k_agg_gemm(const unsigned* __restrict__ x,
        const int* __restrict__ rp, const int* __restrict__ srcs,
        const short* __restrict__ WT, const float* __restrict__ bias,
        unsigned short* __restrict__ out, float* __restrict__ part) {
    __shared__ __align__(16) short Al[64 * 136];
    __shared__ float lsum[HH], lsq[HH];
    int tid = threadIdx.x;
    int row0 = blockIdx.x * 64;
    if (tid < HH) { lsum[tid] = 0.f; lsq[tid] = 0.f; }
    int wave = tid >> 6;
    int lane = tid & 63;
    // gather phase: wave handles rows [wave*16, wave*16+16)
    #pragma unroll 1
    for (int rr = 0; rr < 16; ++rr) {
        int r = wave * 16 + rr;
        int w = row0 + r;
        unsigned* dstu = (unsigned*)&Al[r * 136];
        if (w < NN) {
            int beg = rp[w], end = rp[w + 1];
            unsigned us = x[(size_t)w * 64 + lane];
            float ax = bflo(us), ay = bfhi(us);
            float bx = 0.f, by = 0.f;
            float cx = 0.f, cy = 0.f;
            float dx = 0.f, dy = 0.f;
            int p = beg;
            for (; p + 16 <= end; p += 16) {
                int s0 = srcs[p + 0], s1 = srcs[p + 1], s2 = srcs[p + 2], s3 = srcs[p + 3];
                int s4 = srcs[p + 4], s5 = srcs[p + 5], s6 = srcs[p + 6], s7 = srcs[p + 7];
                int s8 = srcs[p + 8], s9 = srcs[p + 9], sa = srcs[p + 10], sb = srcs[p + 11];
                int sc_ = srcs[p + 12], sd = srcs[p + 13], se = srcs[p + 14], sf = srcs[p + 15];
                unsigned u0 = x[(size_t)s0 * 64 + lane];
                unsigned u1 = x[(size_t)s1 * 64 + lane];
                unsigned u2 = x[(size_t)s2 * 64 + lane];
                unsigned u3 = x[(size_t)s3 * 64 + lane];
                unsigned u4 = x[(size_t)s4 * 64 + lane];
                unsigned u5 = x[(size_t)s5 * 64 + lane];
                unsigned u6 = x[(size_t)s6 * 64 + lane];
                unsigned u7 = x[(size_t)s7 * 64 + lane];
                unsigned u8 = x[(size_t)s8 * 64 + lane];
                unsigned u9 = x[(size_t)s9 * 64 + lane];
                unsigned ua = x[(size_t)sa * 64 + lane];
                unsigned ub = x[(size_t)sb * 64 + lane];
                unsigned uc = x[(size_t)sc_ * 64 + lane];
                unsigned ud = x[(size_t)sd * 64 + lane];
                unsigned ue = x[(size_t)se * 64 + lane];
                unsigned uf = x[(size_t)sf * 64 + lane];
                ax += (bflo(u0) + bflo(u1)) + (bflo(u2) + bflo(u3));
                ay += (bfhi(u0) + bfhi(u1)) + (bfhi(u2) + bfhi(u3));
                bx += (bflo(u4) + bflo(u5)) + (bflo(u6) + bflo(u7));
                by += (bfhi(u4) + bfhi(u5)) + (bfhi(u6) + bfhi(u7));
                cx += (bflo(u8) + bflo(u9)) + (bflo(ua) + bflo(ub));
                cy += (bfhi(u8) + bfhi(u9)) + (bfhi(ua) + bfhi(ub));
                dx += (bflo(uc) + bflo(ud)) + (bflo(ue) + bflo(uf));
                dy += (bfhi(uc) + bfhi(ud)) + (bfhi(ue) + bfhi(uf));
            }
            for (; p + 8 <= end; p += 8) {
                int s0 = srcs[p + 0], s1 = srcs[p + 1], s2 = srcs[p + 2], s3 = srcs[p + 3];
                int s4 = srcs[p + 4], s5 = srcs[p + 5], s6 = srcs[p + 6], s7 = srcs[p + 7];
                unsigned u0 = x[(size_t)s0 * 64 + lane];
                unsigned u1 = x[(size_t)s1 * 64 + lane];
                unsigned u2 = x[(size_t)s2 * 64 + lane];
                unsigned u3 = x[(size_t)s3 * 64 + lane];
                unsigned u4 = x[(size_t)s4 * 64 + lane];
                unsigned u5 = x[(size_t)s5 * 64 + lane];
                unsigned u6 = x[(size_t)s6 * 64 + lane];
                unsigned u7 = x[(size_t)s7 * 64 + lane];
                ax += (bflo(u0) + bflo(u1)) + (bflo(u2) + bflo(u3));
                ay += (bfhi(u0) + bfhi(u1)) + (bfhi(u2) + bfhi(u3));
                bx += (bflo(u4) + bflo(u5)) + (bflo(u6) + bflo(u7));
                by += (bfhi(u4) + bfhi(u5)) + (bfhi(u6) + bfhi(u7));
            }
            for (; p < end; ++p) {
                unsigned u = x[(size_t)srcs[p] * 64 + lane];
                ax += bflo(u);
                ay += bfhi(u);
            }
            ax += bx + cx + dx;
            ay += by + cy + dy;
            dstu[lane] = f2bfu(ax) | (f2bfu(ay) << 16);
        } else {
            dstu[lane] = 0u;
        }
    }
    __syncthreads();
    // MFMA phase
    int ln = lane & 15, quad = lane >> 4;
    int wcol0 = wave * 32;
    f32x4 acc[4][2];
    #pragma unroll
    for (int rt = 0; rt < 4; rt++)
        #pragma unroll
        for (int ct = 0; ct < 2; ct++) acc[rt][ct] = (f32x4){0.f, 0.f, 0.f, 0.f};
    #pragma unroll
    for (int ks = 0; ks < 4; ks++) {
        bf16x8 a[4], b[2];
        #pragma unroll
        for (int ct = 0; ct < 2; ct++)
            b[ct] = *(const bf16x8*)(WT + (size_t)(wcol0 + ct * 16 + ln) * HH + ks * 32 + quad * 8);
        #pragma unroll
        for (int rt = 0; rt < 4; rt++)
            a[rt] = *(const bf16x8*)(&Al[(rt * 16 + ln) * 136 + ks * 32 + quad * 8]);
        #pragma unroll
        for (int rt = 0; rt < 4; rt++)
            #pragma unroll
            for (int ct = 0; ct < 2; ct++)
                acc[rt][ct] = __builtin_amdgcn_mfma_f32_16x16x32_bf16(a[rt], b[ct], acc[rt][ct], 0, 0, 0);
    }
    float b0 = bias[wcol0 + ln];
    float b1 = bias[wcol0 + 16 + ln];
    float s[2] = {0.f, 0.f}, s2[2] = {0.f, 0.f};
    #pragma unroll
    for (int rt = 0; rt < 4; rt++) {
        #pragma unroll
        for (int r = 0; r < 4; r++) {
            int grow = row0 + rt * 16 + quad * 4 + r;
            if (grow < NN) {
                float hv0 = acc[rt][0][r] + b0;
                float hv1 = acc[rt][1][r] + b1;
                out[(size_t)grow * HH + wcol0 + ln] = (unsigned short)f2bfu(hv0);
                out[(size_t)grow * HH + wcol0 + 16 + ln] = (unsigned short)f2bfu(hv1);
                s[0] += hv0; s2[0] = fmaf(hv0, hv0, s2[0]);
                s[1] += hv1; s2[1] = fmaf(hv1, hv1, s2[1]);
            }
        }
    }
    atomicAdd(&lsum[wcol0 + ln], s[0]);
    atomicAdd(&lsum[wcol0 + 16 + ln], s[1]);
    atomicAdd(&lsq[wcol0 + ln], s2[0]);
    atomicAdd(&lsq[wcol0 + 16 + ln], s2[1]);
    __syncthreads();
    if (tid < HH) {
        part[(size_t)blockIdx.x * 256 + tid] = lsum[tid];
        part[(size_t)blockIdx.x * 256 + 128 + tid] = lsq[tid];
    }
}

// ---------------- GEMM K=19 (fp32 compute, bf16 in [NN][32], bf16 out) ----------------
template<int K, bool STATS>
__global__ __launch_bounds__(256) void k_gemm_small(const unsigned short* __restrict__ in,
        const float* __restrict__ W, const float* __restrict__ bias,
        unsigned short* __restrict__ out, float* __restrict__ part) {
    constexpr int SK = ((K + 3) / 4) * 4 + 4;
    __shared__ __align__(16) float yt[32 * SK];
    __shared__ float red[256];
    int tid = threadIdx.x;
    int row0 = blockIdx.x * 32;
    for (int t = tid; t < 32 * SK; t += 256) {
        int r = t / SK, k = t - r * SK;
        float v = 0.f;
        if (k < K) v = bfu2f(in[(size_t)(row0 + r) * 32 + k]);
        yt[t] = v;
    }
    __syncthreads();
    int col = tid & 127;
    int rg = tid >> 7;
    float acc[16];
    #pragma unroll
    for (int r = 0; r < 16; r++) acc[r] = 0.f;
    const float* ybase = &yt[rg * 16 * SK];
    int kk = 0;
    for (; kk + 4 <= K; kk += 4) {
        float w0 = W[(kk + 0) * HH + col];
        float w1 = W[(kk + 1) * HH + col];
        float w2 = W[(kk + 2) * HH + col];
        float w3 = W[(kk + 3) * HH + col];
        #pragma unroll
        for (int r = 0; r < 16; r++) {
            const float4 v = *(const float4*)&ybase[r * SK + kk];
            acc[r] = fmaf(v.x, w0, acc[r]);
            acc[r] = fmaf(v.y, w1, acc[r]);
            acc[r] = fmaf(v.z, w2, acc[r]);
            acc[r] = fmaf(v.w, w3, acc[r]);
        }
    }
    if constexpr (K % 4 != 0) {
        float w[4];
        #pragma unroll
        for (int j = 0; j < 4; j++) w[j] = (kk + j < K) ? W[(kk + j) * HH + col] : 0.f;
        #pragma unroll
        for (int r = 0; r < 16; r++) {
            const float4 v = *(const float4*)&ybase[r * SK + kk];
            acc[r] = fmaf(v.x, w[0], acc[r]);
            acc[r] = fmaf(v.y, w[1], acc[r]);
            acc[r] = fmaf(v.z, w[2], acc[r]);
            acc[r] = fmaf(v.w, w[3], acc[r]);
        }
    }
    float bcol = bias[col];
    float s = 0.f, s2 = 0.f;
    #pragma unroll
    for (int r = 0; r < 16; r++) {
        float hv = acc[r] + bcol;
        out[(size_t)(row0 + rg * 16 + r) * HH + col] = (unsigned short)f2bfu(hv);
        if (STATS) { s += hv; s2 = fmaf(hv, hv, s2); }
    }
    if (STATS) {
        red[tid] = s; __syncthreads();
        if (tid < 128) part[(size_t)blockIdx.x * 256 + tid] = s + red[tid + 128];
        __syncthreads();
        red[tid] = s2; __syncthreads();
        if (tid < 128) part[(size_t)blockIdx.x * 256 + 128 + tid] = s2 + red[tid + 128];
    }
}

// ---------------- K=128 GEMM via bf16 MFMA (BN+ReLU staging, ELU out) ----------------
template<bool STATS, bool BNIN, bool ELUOUT>
__global__ __launch_bounds__(256) void k_gemm_mfma(const unsigned short* __restrict__ in,
        const short* __restrict__ WT, const float* __restrict__ bias,
        const float* __restrict__ bnscale, const float* __restrict__ bnshift,
        unsigned short* __restrict__ out, float* __restrict__ part) {
    __shared__ __align__(16) short Al[64 * 136];
    __shared__ float lsum[HH], lsq[HH];
    int tid = threadIdx.x;
    int row0 = blockIdx.x * 64;
    if (STATS && tid < HH) { lsum[tid] = 0.f; lsq[tid] = 0.f; }
    {
        int r = tid >> 2;
        int k0 = (tid & 3) * 32;
        int grow = row0 + r;
        short* dst = &Al[r * 136 + k0];
        if (grow < NN) {
            const uint4* s4 = (const uint4*)(in + (size_t)grow * HH + k0);
            if constexpr (!BNIN) {
                uint4* d4 = (uint4*)dst;
                d4[0] = s4[0]; d4[1] = s4[1]; d4[2] = s4[2]; d4[3] = s4[3];
            } else {
                unsigned* d = (unsigned*)dst;
                #pragma unroll
                for (int q = 0; q < 4; q++) {
                    uint4 u = s4[q];
                    float4 sc0 = *(const float4*)(bnscale + k0 + q * 8);
                    float4 sh0 = *(const float4*)(bnshift + k0 + q * 8);
                    float4 sc1 = *(const float4*)(bnscale + k0 + q * 8 + 4);
                    float4 sh1 = *(const float4*)(bnshift + k0 + q * 8 + 4);
                    float a0 = bflo(u.x), a1 = bfhi(u.x);
                    float a2 = bflo(u.y), a3 = bfhi(u.y);
                    float a4 = bflo(u.z), a5 = bfhi(u.z);
                    float a6 = bflo(u.w), a7 = bfhi(u.w);
                    a0 = fmaxf(fmaf(a0, sc0.x, sh0.x), 0.f);
                    a1 = fmaxf(fmaf(a1, sc0.y, sh0.y), 0.f);
                    a2 = fmaxf(fmaf(a2, sc0.z, sh0.z), 0.f);
                    a3 = fmaxf(fmaf(a3, sc0.w, sh0.w), 0.f);
                    a4 = fmaxf(fmaf(a4, sc1.x, sh1.x), 0.f);
                    a5 = fmaxf(fmaf(a5, sc1.y, sh1.y), 0.f);
                    a6 = fmaxf(fmaf(a6, sc1.z, sh1.z), 0.f);
                    a7 = fmaxf(fmaf(a7, sc1.w, sh1.w), 0.f);
                    d[q * 4 + 0] = f2bfu(a0) | (f2bfu(a1) << 16);
                    d[q * 4 + 1] = f2bfu(a2) | (f2bfu(a3) << 16);
                    d[q * 4 + 2] = f2bfu(a4) | (f2bfu(a5) << 16);
                    d[q * 4 + 3] = f2bfu(a6) | (f2bfu(a7) << 16);
                }
            }
        } else {
            uint4 z = {0, 0, 0, 0};
            uint4* d4 = (uint4*)dst;
            d4[0] = z; d4[1] = z; d4[2] = z; d4[3] = z;
        }
    }
    __syncthreads();
    int wave = tid >> 6;
    int lane = tid & 63;
    int ln = lane & 15, quad = lane >> 4;
    int wcol0 = wave * 32;
    f32x4 acc[4][2];
    #pragma unroll
    for (int rt = 0; rt < 4; rt++)
        #pragma unroll
        for (int ct = 0; ct < 2; ct++) acc[rt][ct] = (f32x4){0.f, 0.f, 0.f, 0.f};
    #pragma unroll
    for (int ks = 0; ks < 4; ks++) {
        bf16x8 a[4], b[2];
        #pragma unroll
        for (int ct = 0; ct < 2; ct++)
            b[ct] = *(const bf16x8*)(WT + (size_t)(wcol0 + ct * 16 + ln) * HH + ks * 32 + quad * 8);
        #pragma unroll
        for (int rt = 0; rt < 4; rt++)
            a[rt] = *(const bf16x8*)(&Al[(rt * 16 + ln) * 136 + ks * 32 + quad * 8]);
        #pragma unroll
        for (int rt = 0; rt < 4; rt++)
            #pragma unroll
            for (int ct = 0; ct < 2; ct++)
                acc[rt][ct] = __builtin_amdgcn_mfma_f32_16x16x32_bf16(a[rt], b[ct], acc[rt][ct], 0, 0, 0);
    }
    float b0 = bias[wcol0 + ln];
    float b1 = bias[wcol0 + 16 + ln];
    float s[2] = {0.f, 0.f}, s2[2] = {0.f, 0.f};
    #pragma unroll
    for (int rt = 0; rt < 4; rt++) {
        #pragma unroll
        for (int r = 0; r < 4; r++) {
            int grow = row0 + rt * 16 + quad * 4 + r;
            if (grow < NN) {
                float hv0 = acc[rt][0][r] + b0;
                float hv1 = acc[rt][1][r] + b1;
                if (ELUOUT) { hv0 = elu01f(hv0); hv1 = elu01f(hv1); }
                out[(size_t)grow * HH + wcol0 + ln] = (unsigned short)f2bfu(hv0);
                out[(size_t)grow * HH + wcol0 + 16 + ln] = (unsigned short)f2bfu(hv1);
                if (STATS) {
                    s[0] += hv0; s2[0] = fmaf(hv0, hv0, s2[0]);
                    s[1] += hv1; s2[1] = fmaf(hv1, hv1, s2[1]);
                }
            }
        }
    }
    if (STATS) {
        atomicAdd(&lsum[wcol0 + ln], s[0]);
        atomicAdd(&lsum[wcol0 + 16 + ln], s[1]);
        atomicAdd(&lsq[wcol0 + ln], s2[0]);
        atomicAdd(&lsq[wcol0 + 16 + ln], s2[1]);
        __syncthreads();
        if (tid < HH) {
            part[(size_t)blockIdx.x * 256 + tid] = lsum[tid];
            part[(size_t)blockIdx.x * 256 + 128 + tid] = lsq[tid];
        }
    }
}

// stage-1 stat reduce
__global__ __launch_bounds__(256) void k_statred(const float* __restrict__ part, float* __restrict__ part2,
                                                 int nrows) {
    int tid = threadIdx.x;
    float acc = 0.f;
    for (int r = blockIdx.x; r < nrows; r += 64)
        acc += part[(size_t)r * 256 + tid];
    part2[(size_t)blockIdx.x * 256 + tid] = acc;
}

__global__ void k_bnfin(const float* __restrict__ part2, const float* __restrict__ gm,
                        const float* __restrict__ bt, float* scale, float* shift) {
    int c = threadIdx.x;
    float s = 0.f, s2 = 0.f;
    #pragma unroll 4
    for (int j = 0; j < 64; ++j) {
        s += part2[(size_t)j * 256 + c];
        s2 += part2[(size_t)j * 256 + 128 + c];
    }
    float mu = s * (1.f / NN);
    float var = fmaxf(s2 * (1.f / NN) - mu * mu, 0.f);
    float a = gm[c] * rsqrtf(var + BN_EPS);
    scale[c] = a;
    shift[c] = fmaf(-mu, a, bt[c]);
}

// ---------------- pooling (bf16 input) ----------------
__global__ __launch_bounds__(128) void k_pool_part(const unsigned short* __restrict__ x,
                                                   const int* __restrict__ gptr,
                                                   float* __restrict__ psum, float* __restrict__ pmax) {
    int g = blockIdx.x >> 4;
    int ch = blockIdx.x & 15;
    int s = gptr[g], e = gptr[g + 1];
    int len = e - s;
    int per = (len + PCH - 1) / PCH;
    int lo = s + ch * per;
    int hi = min(lo + per, e);
    int c = threadIdx.x;
    float sm = 0.f, mx = -INFINITY;
    for (int i = lo; i < hi; ++i) {
        float v = bfu2f(x[(size_t)i * HH + c]);
        sm += v; mx = fmaxf(mx, v);
    }
    psum[(size_t)blockIdx.x * HH + c] = sm;
    pmax[(size_t)blockIdx.x * HH + c] = mx;
}

// pool finalize + classifier layer 1 fused
__global__ __launch_bounds__(128) void k_pool_cls1(const float* __restrict__ psum, const float* __restrict__ pmax,
                                                   const int* __restrict__ gptr, const float* __restrict__ g0,
                                                   const float* __restrict__ cw1, const float* __restrict__ cb1,
                                                   float* __restrict__ z1) {
    __shared__ float zr[264];
    int g = blockIdx.x, c = threadIdx.x;
    float sm = 0.f, mx = -INFINITY;
    for (int ch = 0; ch < PCH; ++ch) {
        sm += psum[(size_t)(g * PCH + ch) * HH + c];
        mx = fmaxf(mx, pmax[(size_t)(g * PCH + ch) * HH + c]);
    }
    int cntn = gptr[g + 1] - gptr[g];
    zr[c] = sm / (float)max(cntn, 1);
    zr[128 + c] = mx;
    if (c < GG) zr[256 + c] = g0[g * GG + c];
    __syncthreads();
    float acc = cb1[c];
    for (int k = 0; k < 264; ++k) acc = fmaf(zr[k], cw1[k * HH + c], acc);
    z1[g * HH + c] = elu01f(acc);
}

__global__ __launch_bounds__(128) void k_cls2(const float* __restrict__ z1, const float* __restrict__ cgm,
                                              const float* __restrict__ cbt, const float* __restrict__ cw2,
                                              const float* __restrict__ cb2, float* __restrict__ outp) {
    __shared__ float zn[HH * 65];
    int c = threadIdx.x;
    float s = 0.f, s2 = 0.f;
    for (int g = 0; g < BB; ++g) {
        float v = z1[g * HH + c];
        s += v; s2 = fmaf(v, v, s2);
    }
    float mu = s * (1.f / BB);
    float var = fmaxf(s2 * (1.f / BB) - mu * mu, 0.f);
    float a = cgm[c] * rsqrtf(var + BN_EPS);
    float sh = fmaf(-mu, a, cbt[c]);
    for (int g = 0; g < BB; ++g) zn[c * 65 + g] = fmaf(z1[g * HH + c], a, sh);
    __syncthreads();
    if (c < BB) {
        float l0 = cb2[0], l1 = cb2[1];
        for (int k = 0; k < HH; ++k) {
            float v = zn[k * 65 + c];
            l0 = fmaf(v, cw2[k * 2 + 0], l0);
            l1 = fmaf(v, cw2[k * 2 + 1], l1);
        }
        float m = fmaxf(l0, l1);
        float e0 = __expf(l0 - m), e1 = __expf(l1 - m);
        float inv = 1.f / (e0 + e1);
        outp[c * 2 + 0] = e0 * inv;
        outp[c * 2 + 1] = e1 * inv;
    }
}

extern "C" void kernel_launch(void* const* d_in, const int* in_sizes, int n_in,
                              void* d_out, int out_size, void* d_ws, size_t ws_size,
                              hipStream_t stream) {
    (void)in_sizes; (void)n_in; (void)out_size; (void)ws_size;
    const float* h0     = (const float*)d_in[0];
    const float* coord0 = (const float*)d_in[1];
    const float* g0     = (const float*)d_in[2];
    const int*   eidx   = (const int*)d_in[3];
    const int*   batch  = (const int*)d_in[4];
    const float* w1_0   = (const float*)d_in[5];
    const float* b1_0   = (const float*)d_in[6];
    const float* gm_0   = (const float*)d_in[7];
    const float* bt_0   = (const float*)d_in[8];
    const float* w2_0   = (const float*)d_in[9];
    const float* b2_0   = (const float*)d_in[10];
    const float* w1_r   = (const float*)d_in[11];
    const float* b1_r   = (const float*)d_in[12];
    const float* gm_r   = (const float*)d_in[13];
    const float* bt_r   = (const float*)d_in[14];
    const float* w2_r   = (const float*)d_in[15];
    const float* b2_r   = (const float*)d_in[16];
    const float* cw1    = (const float*)d_in[17];
    const float* cb1    = (const float*)d_in[18];
    const float* cgm    = (const float*)d_in[19];
    const float* cbt    = (const float*)d_in[20];
    const float* cw2    = (const float*)d_in[21];
    const float* cb2    = (const float*)d_in[22];
    float* outp = (float*)d_out;

    const int* esrc = eidx;
    const int* edst = eidx + EE;

    char* p = (char*)d_ws;
    auto alloc = [&](size_t bytes) { void* r = (void*)p; p += (bytes + 255) & ~(size_t)255; return r; };
    unsigned short* x0bf     = (unsigned short*)alloc((size_t)NN * 32 * 2);   // [NN][32] bf16
    unsigned short* y19bf    = (unsigned short*)alloc((size_t)NN * 32 * 2);
    unsigned short* hbf      = (unsigned short*)alloc((size_t)NN * HH * 2);
    unsigned*       xbf      = (unsigned*)alloc((size_t)NN * 64 * 4);
    int*            rp       = (int*)alloc((size_t)(NN + 1) * 4);
    int*            srcs     = (int*)alloc((size_t)EE * 4);
    int*            bincnt   = (int*)alloc((size_t)NBINS * 4);
    int*            binstart = (int*)alloc((size_t)NBINS * 4);
    int*            gptr     = (int*)alloc((BB + 1) * 4);
    short*          wt       = (short*)alloc((size_t)5 * HH * HH * 2);
    float*          part     = (float*)alloc((size_t)3125 * 256 * 4);
    float*          part2    = (float*)alloc((size_t)64 * 256 * 4);
    float*          bnscale  = (float*)alloc(HH * 4);
    float*          bnshift  = (float*)alloc(HH * 4);
    float*          psum     = (float*)alloc((size_t)BB * PCH * HH * 4);
    float*          pmax     = (float*)alloc((size_t)BB * PCH * HH * 4);
    float*          z1b      = (float*)alloc((size_t)BB * HH * 4);
    uint2*          binbuf   = (uint2*)alloc((size_t)NBINS * BCAP * 8);   // 25.7 MB

    const int NB_A = (EE + ACH - 1) / ACH;          // 782
    const int NB_AGG = (NN * 64 + 255) / 256;       // 25000
    const int NB_G32 = NN / 32;                     // 3125
    const int NB_G64 = (NN + 63) / 64;              // 1563
    const int NB_X0 = (NN * 32 + 255) / 256;        // 12500
    const int NB_WP = (5 * HH * HH + 255) / 256;    // 320

    // CSR build (LDS counting sort) + weight prep
    hipMemsetAsync(bincnt, 0, (size_t)NBINS * 4, stream);
    k_binA<<<NB_A, 256, 0, stream>>>(esrc, edst, bincnt, binbuf);
    k_binscan<<<1, 512, 0, stream>>>(bincnt, binstart, rp, batch, gptr);
    k_binB<<<NBINS, 256, 0, stream>>>(binbuf, bincnt, binstart, rp, srcs);
    k_wprep<<<NB_WP, 256, 0, stream>>>(w2_0, w1_r, w2_r, wt);

    // layer 0 (bf16 19-dim path, fp32 accumulate)
    k_buildx0<<<NB_X0, 256, 0, stream>>>(h0, coord0, x0bf);
    k_agg_small<<<NB_AGG, 256, 0, stream>>>((const uint4*)x0bf, rp, srcs, (uint4*)y19bf);
    k_gemm_small<K0, true><<<NB_G32, 256, 0, stream>>>(y19bf, w1_0, b1_0, hbf, part);
    k_statred<<<64, 256, 0, stream>>>(part, part2, NB_G32);
    k_bnfin<<<1, 128, 0, stream>>>(part2, gm_0, bt_0, bnscale, bnshift);
    k_gemm_mfma<false, true, true><<<NB_G64, 256, 0, stream>>>(hbf, wt, b2_0, bnscale, bnshift,
                                                               (unsigned short*)xbf, nullptr);

    // layers 1..2: fused gather+GEMM1, then GEMM2
    for (int i = 0; i < 2; ++i) {
        k_agg_gemm<<<NB_G64, 256, 0, stream>>>(xbf, rp, srcs,
                wt + (size_t)(1 + i) * HH * HH, b1_r + i * HH, hbf, part);
        k_statred<<<64, 256, 0, stream>>>(part, part2, NB_G64);
        k_bnfin<<<1, 128, 0, stream>>>(part2, gm_r + i * HH, bt_r + i * HH, bnscale, bnshift);
        k_gemm_mfma<false, true, true><<<NB_G64, 256, 0, stream>>>(hbf,
                wt + (size_t)(3 + i) * HH * HH, b2_r + i * HH, bnscale, bnshift,
                (unsigned short*)xbf, nullptr);
    }

    // pooling + classifier
    k_pool_part<<<BB * PCH, 128, 0, stream>>>((const unsigned short*)xbf, gptr, psum, pmax);
    k_pool_cls1<<<BB, 128, 0, stream>>>(psum, pmax, gptr, g0, cw1, cb1, z1b);
    k_cls2<<<1, 128, 0, stream>>>(z1b, cgm, cbt, cw2, cb2, outp);
}

// Round 14
// 594.951 us; speedup vs baseline: 1.1322x; 1.1322x over previous
//
#include <hip/hip_runtime.h>
#include <math.h>

#define NN 100000
#define EE 1600000
#define BB 64
#define FF 16
#define HH 128
#define GG 8
#define K0 19
#define BN_EPS 1e-5f
#define PCH 16
#define BSHIFT 8
#define BNODES 256
#define NBINS 391          // ceil(NN/256)
#define BCAP 8192
#define ACH 2048           // edges per phase-A block

typedef short bf16x8 __attribute__((ext_vector_type(8)));
typedef float f32x4 __attribute__((ext_vector_type(4)));

__device__ __forceinline__ float elu01f(float v) {
    return v > 0.f ? v : 0.1f * (__expf(v) - 1.f);
}

__device__ __forceinline__ unsigned f2bfu(float f) {
    unsigned u = __float_as_uint(f);
    unsigned r = u + 0x7FFFu + ((u >> 16) & 1u);
    return r >> 16;
}
__device__ __forceinline__ short f2bf(float f) { return (short)f2bfu(f); }
__device__ __forceinline__ float bfu2f(unsigned short b) {
    return __uint_as_float(((unsigned)b) << 16);
}
__device__ __forceinline__ float bflo(unsigned u) { return __uint_as_float(u << 16); }
__device__ __forceinline__ float bfhi(unsigned u) { return __uint_as_float(u & 0xffff0000u); }

// ---------------- CSR build: 2-phase LDS counting sort ----------------
__global__ __launch_bounds__(256) void k_binA(const int* __restrict__ esrc, const int* __restrict__ edst,
                                              int* __restrict__ bincnt, uint2* __restrict__ binbuf) {
    __shared__ int hist[NBINS];
    __shared__ int gbase[NBINS];
    __shared__ int cur[NBINS];
    __shared__ int sc[512];
    __shared__ uint2 ebuf[ACH];
    __shared__ uint2 sorted[ACH];
    int tid = threadIdx.x;
    int e0 = blockIdx.x * ACH;
    int n = min(ACH, EE - e0);
    for (int i = tid; i < NBINS; i += 256) hist[i] = 0;
    __syncthreads();
    for (int i = tid; i < n; i += 256) {
        int s = esrc[e0 + i];
        int d = edst[e0 + i];
        ebuf[i] = make_uint2((unsigned)s, (unsigned)d);
        atomicAdd(&hist[d >> BSHIFT], 1);
    }
    __syncthreads();
    sc[tid] = (tid < NBINS) ? hist[tid] : 0;
    sc[tid + 256] = (tid + 256 < NBINS) ? hist[tid + 256] : 0;
    __syncthreads();
    for (int off = 1; off < 512; off <<= 1) {
        int a0 = sc[tid], a1 = sc[tid + 256];
        int b0 = (tid >= off) ? sc[tid - off] : 0;
        int b1 = (tid + 256 >= off) ? sc[tid + 256 - off] : 0;
        __syncthreads();
        sc[tid] = a0 + b0;
        sc[tid + 256] = a1 + b1;
        __syncthreads();
    }
    for (int b = tid; b < NBINS; b += 256) {
        int c = hist[b];
        gbase[b] = (c > 0) ? atomicAdd(&bincnt[b], c) : 0;
        cur[b] = (b > 0) ? sc[b - 1] : 0;
    }
    __syncthreads();
    for (int i = tid; i < n; i += 256) {
        uint2 e = ebuf[i];
        int b = (int)(e.y >> BSHIFT);
        int pos = atomicAdd(&cur[b], 1);
        sorted[pos] = e;
    }
    __syncthreads();
    for (int i = tid; i < n; i += 256) {
        uint2 e = sorted[i];
        int b = (int)(e.y >> BSHIFT);
        int ls = (b > 0) ? sc[b - 1] : 0;
        int gpos = gbase[b] + (i - ls);
        binbuf[(size_t)b * BCAP + gpos] = e;
    }
}

// binscan + gptr fused
__global__ void k_binscan(const int* __restrict__ bincnt, int* __restrict__ binstart, int* __restrict__ rp,
                          const int* __restrict__ batch, int* __restrict__ gptr) {
    __shared__ int sc[512];
    int t = threadIdx.x;
    sc[t] = (t < NBINS) ? bincnt[t] : 0;
    __syncthreads();
    for (int off = 1; off < 512; off <<= 1) {
        int v = (t >= off) ? sc[t - off] : 0;
        __syncthreads();
        sc[t] += v;
        __syncthreads();
    }
    if (t < NBINS) binstart[t] = (t > 0) ? sc[t - 1] : 0;
    if (t == 0) rp[NN] = EE;
    if (t <= BB) {
        int lo = 0, hi = NN;
        while (lo < hi) { int mid = (lo + hi) >> 1; if (batch[mid] < t) lo = mid + 1; else hi = mid; }
        gptr[t] = lo;
    }
}

__global__ __launch_bounds__(256) void k_binB(const uint2* __restrict__ binbuf, const int* __restrict__ bincnt,
                                              const int* __restrict__ binstart,
                                              int* __restrict__ rp, int* __restrict__ srcs) {
    __shared__ int hist[BNODES];
    __shared__ int scx[BNODES];
    __shared__ int scur[BNODES];
    __shared__ int sbuf[BCAP];
    int b = blockIdx.x;
    int n = bincnt[b];
    int tid = threadIdx.x;
    hist[tid] = 0;
    __syncthreads();
    const uint2* eb = binbuf + (size_t)b * BCAP;
    for (int i = tid; i < n; i += 256)
        atomicAdd(&hist[eb[i].y & (BNODES - 1)], 1);
    __syncthreads();
    scx[tid] = hist[tid];
    __syncthreads();
    for (int off = 1; off < 256; off <<= 1) {
        int v = (tid >= off) ? scx[tid - off] : 0;
        __syncthreads();
        scx[tid] += v;
        __syncthreads();
    }
    int base = binstart[b];
    int excl = (tid > 0) ? scx[tid - 1] : 0;
    int node = (b << BSHIFT) + tid;
    if (node < NN) rp[node] = base + excl;
    scur[tid] = excl;
    __syncthreads();
    for (int i = tid; i < n; i += 256) {
        uint2 e = eb[i];
        int pos = atomicAdd(&scur[e.y & (BNODES - 1)], 1);
        sbuf[pos] = (int)e.x;
    }
    __syncthreads();
    for (int i = tid; i < n; i += 256) srcs[base + i] = sbuf[i];
}

// ---------------- weight prep: fp32 [k][col] -> bf16 transposed [col][k] ----------------
__global__ __launch_bounds__(256) void k_wprep(const float* __restrict__ w2_0, const float* __restrict__ w1_r,
                                               const float* __restrict__ w2_r, short* __restrict__ wt) {
    int t = blockIdx.x * 256 + threadIdx.x;
    if (t >= 5 * HH * HH) return;
    int m = t >> 14;
    int rem = t & 16383;
    int col = rem >> 7;
    int k = rem & 127;
    const float* src = (m == 0) ? w2_0 : (m <= 2 ? w1_r + (size_t)(m - 1) * HH * HH
                                                 : w2_r + (size_t)(m - 3) * HH * HH);
    wt[t] = f2bf(src[k * HH + col]);
}

// ---------------- feature build (bf16, rows padded to 32 ch = 64B) ----------------
__global__ __launch_bounds__(256) void k_buildx0(const float* __restrict__ h0, const float* __restrict__ coord,
                                                 unsigned short* __restrict__ x0) {
    int i = blockIdx.x * 256 + threadIdx.x;
    if (i >= NN * 32) return;
    int node = i >> 5, k = i & 31;
    float v = 0.f;
    if (k < FF) v = h0[node * FF + k];
    else if (k < K0) v = coord[node * 3 + (k - FF)];
    x0[i] = (unsigned short)f2bfu(v);
}

// ---------------- layer-0 aggregation: 16 edges/wave (4 lanes x 16B per row) ----------------
__global__ __launch_bounds__(256) void k_agg_small(const uint4* __restrict__ x, const int* __restrict__ rp,
                                                   const int* __restrict__ srcs, uint4* __restrict__ y) {
    int w = (blockIdx.x * 256 + threadIdx.x) >> 6;
    int lane = threadIdx.x & 63;
    if (w >= NN) return;
    int e = lane >> 2, q = lane & 3;
    int beg = rp[w], end = rp[w + 1];
    float acc[8];
    {
        if (e == 0) {
            uint4 u = x[(size_t)w * 4 + q];
            acc[0] = bflo(u.x); acc[1] = bfhi(u.x);
            acc[2] = bflo(u.y); acc[3] = bfhi(u.y);
            acc[4] = bflo(u.z); acc[5] = bfhi(u.z);
            acc[6] = bflo(u.w); acc[7] = bfhi(u.w);
        } else {
            #pragma unroll
            for (int j = 0; j < 8; j++) acc[j] = 0.f;
        }
    }
    for (int p = beg; p < end; p += 16) {
        int rem = end - p;
        bool act = e < rem;
        int sn = act ? srcs[p + e] : 0;
        uint4 u = x[(size_t)sn * 4 + q];
        float m = act ? 1.f : 0.f;
        acc[0] = fmaf(m, bflo(u.x), acc[0]); acc[1] = fmaf(m, bfhi(u.x), acc[1]);
        acc[2] = fmaf(m, bflo(u.y), acc[2]); acc[3] = fmaf(m, bfhi(u.y), acc[3]);
        acc[4] = fmaf(m, bflo(u.z), acc[4]); acc[5] = fmaf(m, bfhi(u.z), acc[5]);
        acc[6] = fmaf(m, bflo(u.w), acc[6]); acc[7] = fmaf(m, bfhi(u.w), acc[7]);
    }
    #pragma unroll
    for (int mask = 4; mask <= 32; mask <<= 1)
        #pragma unroll
        for (int j = 0; j < 8; j++)
            acc[j] += __shfl_xor(acc[j], mask, 64);
    if (e == 0) {
        uint4 o;
        o.x = f2bfu(acc[0]) | (f2bfu(acc[1]) << 16);
        o.y = f2bfu(acc[2]) | (f2bfu(acc[3]) << 16);
        o.z = f2bfu(acc[4]) | (f2bfu(acc[5]) << 16);
        o.w = f2bfu(acc[6]) | (f2bfu(acc[7]) << 16);
        y[(size_t)w * 4 + q] = o;
    }
}

// bf16 aggregation: one wave per node, 16-deep ILP (best measured: ~70us, 5.9 TB/s service)
__global__ __launch_bounds__(256) void k_agg128_bf(const unsigned* __restrict__ x, const int* __restrict__ rp,
                                                   const int* __restrict__ srcs, unsigned* __restrict__ y) {
    int w = (blockIdx.x * 256 + threadIdx.x) >> 6;
    int lane = threadIdx.x & 63;
    if (w >= NN) return;
    int beg = rp[w], end = rp[w + 1];
    unsigned us = x[(size_t)w * 64 + lane];
    float ax = bflo(us), ay = bfhi(us);
    float bx = 0.f, by = 0.f;
    float cx = 0.f, cy = 0.f;
    float dx = 0.f, dy = 0.f;
    int p = beg;
    for (; p + 16 <= end; p += 16) {
        int s0 = srcs[p + 0], s1 = srcs[p + 1], s2 = srcs[p + 2], s3 = srcs[p + 3];
        int s4 = srcs[p + 4], s5 = srcs[p + 5], s6 = srcs[p + 6], s7 = srcs[p + 7];
        int s8 = srcs[p + 8], s9 = srcs[p + 9], sa = srcs[p + 10], sb = srcs[p + 11];
        int sc_ = srcs[p + 12], sd = srcs[p + 13], se = srcs[p + 14], sf = srcs[p + 15];
        unsigned u0 = x[(size_t)s0 * 64 + lane];
        unsigned u1 = x[(size_t)s1 * 64 + lane];
        unsigned u2 = x[(size_t)s2 * 64 + lane];
        unsigned u3 = x[(size_t)s3 * 64 + lane];
        unsigned u4 = x[(size_t)s4 * 64 + lane];
        unsigned u5 = x[(size_t)s5 * 64 + lane];
        unsigned u6 = x[(size_t)s6 * 64 + lane];
        unsigned u7 = x[(size_t)s7 * 64 + lane];
        unsigned u8 = x[(size_t)s8 * 64 + lane];
        unsigned u9 = x[(size_t)s9 * 64 + lane];
        unsigned ua = x[(size_t)sa * 64 + lane];
        unsigned ub = x[(size_t)sb * 64 + lane];
        unsigned uc = x[(size_t)sc_ * 64 + lane];
        unsigned ud = x[(size_t)sd * 64 + lane];
        unsigned ue = x[(size_t)se * 64 + lane];
        unsigned uf = x[(size_t)sf * 64 + lane];
        ax += (bflo(u0) + bflo(u1)) + (bflo(u2) + bflo(u3));
        ay += (bfhi(u0) + bfhi(u1)) + (bfhi(u2) + bfhi(u3));
        bx += (bflo(u4) + bflo(u5)) + (bflo(u6) + bflo(u7));
        by += (bfhi(u4) + bfhi(u5)) + (bfhi(u6) + bfhi(u7));
        cx += (bflo(u8) + bflo(u9)) + (bflo(ua) + bflo(ub));
        cy += (bfhi(u8) + bfhi(u9)) + (bfhi(ua) + bfhi(ub));
        dx += (bflo(uc) + bflo(ud)) + (bflo(ue) + bflo(uf));
        dy += (bfhi(uc) + bfhi(ud)) + (bfhi(ue) + bfhi(uf));
    }
    for (; p + 8 <= end; p += 8) {
        int s0 = srcs[p + 0], s1 = srcs[p + 1], s2 = srcs[p + 2], s3 = srcs[p + 3];
        int s4 = srcs[p + 4], s5 = srcs[p + 5], s6 = srcs[p + 6], s7 = srcs[p + 7];
        unsigned u0 = x[(size_t)s0 * 64 + lane];
        unsigned u1 = x[(size_t)s1 * 64 + lane];
        unsigned u2 = x[(size_t)s2 * 64 + lane];
        unsigned u3 = x[(size_t)s3 * 64 + lane];
        unsigned u4 = x[(size_t)s4 * 64 + lane];
        unsigned u5 = x[(size_t)s5 * 64 + lane];
        unsigned u6 = x[(size_t)s6 * 64 + lane];
        unsigned u7 = x[(size_t)s7 * 64 + lane];
        ax += (bflo(u0) + bflo(u1)) + (bflo(u2) + bflo(u3));
        ay += (bfhi(u0) + bfhi(u1)) + (bfhi(u2) + bfhi(u3));
        bx += (bflo(u4) + bflo(u5)) + (bflo(u6) + bflo(u7));
        by += (bfhi(u4) + bfhi(u5)) + (bfhi(u6) + bfhi(u7));
    }
    for (; p < end; ++p) {
        unsigned u = x[(size_t)srcs[p] * 64 + lane];
        ax += bflo(u);
        ay += bfhi(u);
    }
    ax += bx + cx + dx;
    ay += by + cy + dy;
    y[(size_t)w * 64 + lane] = f2bfu(ax) | (f2bfu(ay) << 16);
}

// ---------------- GEMM K=19 (fp32 compute, bf16 in [NN][32], bf16 out) ----------------
template<int K, bool STATS>
__global__ __launch_bounds__(256) void k_gemm_small(const unsigned short* __restrict__ in,
        const float* __restrict__ W, const float* __restrict__ bias,
        unsigned short* __restrict__ out, float* __restrict__ part) {
    constexpr int SK = ((K + 3) / 4) * 4 + 4;
    __shared__ __align__(16) float yt[32 * SK];
    __shared__ float red[256];
    int tid = threadIdx.x;
    int row0 = blockIdx.x * 32;
    for (int t = tid; t < 32 * SK; t += 256) {
        int r = t / SK, k = t - r * SK;
        float v = 0.f;
        if (k < K) v = bfu2f(in[(size_t)(row0 + r) * 32 + k]);
        yt[t] = v;
    }
    __syncthreads();
    int col = tid & 127;
    int rg = tid >> 7;
    float acc[16];
    #pragma unroll
    for (int r = 0; r < 16; r++) acc[r] = 0.f;
    const float* ybase = &yt[rg * 16 * SK];
    int kk = 0;
    for (; kk + 4 <= K; kk += 4) {
        float w0 = W[(kk + 0) * HH + col];
        float w1 = W[(kk + 1) * HH + col];
        float w2 = W[(kk + 2) * HH + col];
        float w3 = W[(kk + 3) * HH + col];
        #pragma unroll
        for (int r = 0; r < 16; r++) {
            const float4 v = *(const float4*)&ybase[r * SK + kk];
            acc[r] = fmaf(v.x, w0, acc[r]);
            acc[r] = fmaf(v.y, w1, acc[r]);
            acc[r] = fmaf(v.z, w2, acc[r]);
            acc[r] = fmaf(v.w, w3, acc[r]);
        }
    }
    if constexpr (K % 4 != 0) {
        float w[4];
        #pragma unroll
        for (int j = 0; j < 4; j++) w[j] = (kk + j < K) ? W[(kk + j) * HH + col] : 0.f;
        #pragma unroll
        for (int r = 0; r < 16; r++) {
            const float4 v = *(const float4*)&ybase[r * SK + kk];
            acc[r] = fmaf(v.x, w[0], acc[r]);
            acc[r] = fmaf(v.y, w[1], acc[r]);
            acc[r] = fmaf(v.z, w[2], acc[r]);
            acc[r] = fmaf(v.w, w[3], acc[r]);
        }
    }
    float bcol = bias[col];
    float s = 0.f, s2 = 0.f;
    #pragma unroll
    for (int r = 0; r < 16; r++) {
        float hv = acc[r] + bcol;
        out[(size_t)(row0 + rg * 16 + r) * HH + col] = (unsigned short)f2bfu(hv);
        if (STATS) { s += hv; s2 = fmaf(hv, hv, s2); }
    }
    if (STATS) {
        red[tid] = s; __syncthreads();
        if (tid < 128) part[(size_t)blockIdx.x * 256 + tid] = s + red[tid + 128];
        __syncthreads();
        red[tid] = s2; __syncthreads();
        if (tid < 128) part[(size_t)blockIdx.x * 256 + 128 + tid] = s2 + red[tid + 128];
    }
}

// ---------------- K=128 GEMM via bf16 MFMA (BN+ReLU staging, ELU out) ----------------
template<bool STATS, bool BNIN, bool ELUOUT>
__global__ __launch_bounds__(256) void k_gemm_mfma(const unsigned short* __restrict__ in,
        const short* __restrict__ WT, const float* __restrict__ bias,
        const float* __restrict__ bnscale, const float* __restrict__ bnshift,
        unsigned short* __restrict__ out, float* __restrict__ part) {
    __shared__ __align__(16) short Al[64 * 136];
    __shared__ float lsum[HH], lsq[HH];
    int tid = threadIdx.x;
    int row0 = blockIdx.x * 64;
    if (STATS && tid < HH) { lsum[tid] = 0.f; lsq[tid] = 0.f; }
    {
        int r = tid >> 2;
        int k0 = (tid & 3) * 32;
        int grow = row0 + r;
        short* dst = &Al[r * 136 + k0];
        if (grow < NN) {
            const uint4* s4 = (const uint4*)(in + (size_t)grow * HH + k0);
            if constexpr (!BNIN) {
                uint4* d4 = (uint4*)dst;
                d4[0] = s4[0]; d4[1] = s4[1]; d4[2] = s4[2]; d4[3] = s4[3];
            } else {
                unsigned* d = (unsigned*)dst;
                #pragma unroll
                for (int q = 0; q < 4; q++) {
                    uint4 u = s4[q];
                    float4 sc0 = *(const float4*)(bnscale + k0 + q * 8);
                    float4 sh0 = *(const float4*)(bnshift + k0 + q * 8);
                    float4 sc1 = *(const float4*)(bnscale + k0 + q * 8 + 4);
                    float4 sh1 = *(const float4*)(bnshift + k0 + q * 8 + 4);
                    float a0 = bflo(u.x), a1 = bfhi(u.x);
                    float a2 = bflo(u.y), a3 = bfhi(u.y);
                    float a4 = bflo(u.z), a5 = bfhi(u.z);
                    float a6 = bflo(u.w), a7 = bfhi(u.w);
                    a0 = fmaxf(fmaf(a0, sc0.x, sh0.x), 0.f);
                    a1 = fmaxf(fmaf(a1, sc0.y, sh0.y), 0.f);
                    a2 = fmaxf(fmaf(a2, sc0.z, sh0.z), 0.f);
                    a3 = fmaxf(fmaf(a3, sc0.w, sh0.w), 0.f);
                    a4 = fmaxf(fmaf(a4, sc1.x, sh1.x), 0.f);
                    a5 = fmaxf(fmaf(a5, sc1.y, sh1.y), 0.f);
                    a6 = fmaxf(fmaf(a6, sc1.z, sh1.z), 0.f);
                    a7 = fmaxf(fmaf(a7, sc1.w, sh1.w), 0.f);
                    d[q * 4 + 0] = f2bfu(a0) | (f2bfu(a1) << 16);
                    d[q * 4 + 1] = f2bfu(a2) | (f2bfu(a3) << 16);
                    d[q * 4 + 2] = f2bfu(a4) | (f2bfu(a5) << 16);
                    d[q * 4 + 3] = f2bfu(a6) | (f2bfu(a7) << 16);
                }
            }
        } else {
            uint4 z = {0, 0, 0, 0};
            uint4* d4 = (uint4*)dst;
            d4[0] = z; d4[1] = z; d4[2] = z; d4[3] = z;
        }
    }
    __syncthreads();
    int wave = tid >> 6;
    int lane = tid & 63;
    int ln = lane & 15, quad = lane >> 4;
    int wcol0 = wave * 32;
    f32x4 acc[4][2];
    #pragma unroll
    for (int rt = 0; rt < 4; rt++)
        #pragma unroll
        for (int ct = 0; ct < 2; ct++) acc[rt][ct] = (f32x4){0.f, 0.f, 0.f, 0.f};
    #pragma unroll
    for (int ks = 0; ks < 4; ks++) {
        bf16x8 a[4], b[2];
        #pragma unroll
        for (int ct = 0; ct < 2; ct++)
            b[ct] = *(const bf16x8*)(WT + (size_t)(wcol0 + ct * 16 + ln) * HH + ks * 32 + quad * 8);
        #pragma unroll
        for (int rt = 0; rt < 4; rt++)
            a[rt] = *(const bf16x8*)(&Al[(rt * 16 + ln) * 136 + ks * 32 + quad * 8]);
        #pragma unroll
        for (int rt = 0; rt < 4; rt++)
            #pragma unroll
            for (int ct = 0; ct < 2; ct++)
                acc[rt][ct] = __builtin_amdgcn_mfma_f32_16x16x32_bf16(a[rt], b[ct], acc[rt][ct], 0, 0, 0);
    }
    float b0 = bias[wcol0 + ln];
    float b1 = bias[wcol0 + 16 + ln];
    float s[2] = {0.f, 0.f}, s2[2] = {0.f, 0.f};
    #pragma unroll
    for (int rt = 0; rt < 4; rt++) {
        #pragma unroll
        for (int r = 0; r < 4; r++) {
            int grow = row0 + rt * 16 + quad * 4 + r;
            if (grow < NN) {
                float hv0 = acc[rt][0][r] + b0;
                float hv1 = acc[rt][1][r] + b1;
                if (ELUOUT) { hv0 = elu01f(hv0); hv1 = elu01f(hv1); }
                out[(size_t)grow * HH + wcol0 + ln] = (unsigned short)f2bfu(hv0);
                out[(size_t)grow * HH + wcol0 + 16 + ln] = (unsigned short)f2bfu(hv1);
                if (STATS) {
                    s[0] += hv0; s2[0] = fmaf(hv0, hv0, s2[0]);
                    s[1] += hv1; s2[1] = fmaf(hv1, hv1, s2[1]);
                }
            }
        }
    }
    if (STATS) {
        atomicAdd(&lsum[wcol0 + ln], s[0]);
        atomicAdd(&lsum[wcol0 + 16 + ln], s[1]);
        atomicAdd(&lsq[wcol0 + ln], s2[0]);
        atomicAdd(&lsq[wcol0 + 16 + ln], s2[1]);
        __syncthreads();
        if (tid < HH) {
            part[(size_t)blockIdx.x * 256 + tid] = lsum[tid];
            part[(size_t)blockIdx.x * 256 + 128 + tid] = lsq[tid];
        }
    }
}

// stage-1 stat reduce
__global__ __launch_bounds__(256) void k_statred(const float* __restrict__ part, float* __restrict__ part2,
                                                 int nrows) {
    int tid = threadIdx.x;
    float acc = 0.f;
    for (int r = blockIdx.x; r < nrows; r += 64)
        acc += part[(size_t)r * 256 + tid];
    part2[(size_t)blockIdx.x * 256 + tid] = acc;
}

__global__ void k_bnfin(const float* __restrict__ part2, const float* __restrict__ gm,
                        const float* __restrict__ bt, float* scale, float* shift) {
    int c = threadIdx.x;
    float s = 0.f, s2 = 0.f;
    #pragma unroll 4
    for (int j = 0; j < 64; ++j) {
        s += part2[(size_t)j * 256 + c];
        s2 += part2[(size_t)j * 256 + 128 + c];
    }
    float mu = s * (1.f / NN);
    float var = fmaxf(s2 * (1.f / NN) - mu * mu, 0.f);
    float a = gm[c] * rsqrtf(var + BN_EPS);
    scale[c] = a;
    shift[c] = fmaf(-mu, a, bt[c]);
}

// ---------------- pooling (bf16 input) ----------------
__global__ __launch_bounds__(128) void k_pool_part(const unsigned short* __restrict__ x,
                                                   const int* __restrict__ gptr,
                                                   float* __restrict__ psum, float* __restrict__ pmax) {
    int g = blockIdx.x >> 4;
    int ch = blockIdx.x & 15;
    int s = gptr[g], e = gptr[g + 1];
    int len = e - s;
    int per = (len + PCH - 1) / PCH;
    int lo = s + ch * per;
    int hi = min(lo + per, e);
    int c = threadIdx.x;
    float sm = 0.f, mx = -INFINITY;
    for (int i = lo; i < hi; ++i) {
        float v = bfu2f(x[(size_t)i * HH + c]);
        sm += v; mx = fmaxf(mx, v);
    }
    psum[(size_t)blockIdx.x * HH + c] = sm;
    pmax[(size_t)blockIdx.x * HH + c] = mx;
}

// pool finalize + classifier layer 1 fused
__global__ __launch_bounds__(128) void k_pool_cls1(const float* __restrict__ psum, const float* __restrict__ pmax,
                                                   const int* __restrict__ gptr, const float* __restrict__ g0,
                                                   const float* __restrict__ cw1, const float* __restrict__ cb1,
                                                   float* __restrict__ z1) {
    __shared__ float zr[264];
    int g = blockIdx.x, c = threadIdx.x;
    float sm = 0.f, mx = -INFINITY;
    for (int ch = 0; ch < PCH; ++ch) {
        sm += psum[(size_t)(g * PCH + ch) * HH + c];
        mx = fmaxf(mx, pmax[(size_t)(g * PCH + ch) * HH + c]);
    }
    int cntn = gptr[g + 1] - gptr[g];
    zr[c] = sm / (float)max(cntn, 1);
    zr[128 + c] = mx;
    if (c < GG) zr[256 + c] = g0[g * GG + c];
    __syncthreads();
    float acc = cb1[c];
    for (int k = 0; k < 264; ++k) acc = fmaf(zr[k], cw1[k * HH + c], acc);
    z1[g * HH + c] = elu01f(acc);
}

__global__ __launch_bounds__(128) void k_cls2(const float* __restrict__ z1, const float* __restrict__ cgm,
                                              const float* __restrict__ cbt, const float* __restrict__ cw2,
                                              const float* __restrict__ cb2, float* __restrict__ outp) {
    __shared__ float zn[HH * 65];
    int c = threadIdx.x;
    float s = 0.f, s2 = 0.f;
    for (int g = 0; g < BB; ++g) {
        float v = z1[g * HH + c];
        s += v; s2 = fmaf(v, v, s2);
    }
    float mu = s * (1.f / BB);
    float var = fmaxf(s2 * (1.f / BB) - mu * mu, 0.f);
    float a = cgm[c] * rsqrtf(var + BN_EPS);
    float sh = fmaf(-mu, a, cbt[c]);
    for (int g = 0; g < BB; ++g) zn[c * 65 + g] = fmaf(z1[g * HH + c], a, sh);
    __syncthreads();
    if (c < BB) {
        float l0 = cb2[0], l1 = cb2[1];
        for (int k = 0; k < HH; ++k) {
            float v = zn[k * 65 + c];
            l0 = fmaf(v, cw2[k * 2 + 0], l0);
            l1 = fmaf(v, cw2[k * 2 + 1], l1);
        }
        float m = fmaxf(l0, l1);
        float e0 = __expf(l0 - m), e1 = __expf(l1 - m);
        float inv = 1.f / (e0 + e1);
        outp[c * 2 + 0] = e0 * inv;
        outp[c * 2 + 1] = e1 * inv;
    }
}

extern "C" void kernel_launch(void* const* d_in, const int* in_sizes, int n_in,
                              void* d_out, int out_size, void* d_ws, size_t ws_size,
                              hipStream_t stream) {
    (void)in_sizes; (void)n_in; (void)out_size; (void)ws_size;
    const float* h0     = (const float*)d_in[0];
    const float* coord0 = (const float*)d_in[1];
    const float* g0     = (const float*)d_in[2];
    const int*   eidx   = (const int*)d_in[3];
    const int*   batch  = (const int*)d_in[4];
    const float* w1_0   = (const float*)d_in[5];
    const float* b1_0   = (const float*)d_in[6];
    const float* gm_0   = (const float*)d_in[7];
    const float* bt_0   = (const float*)d_in[8];
    const float* w2_0   = (const float*)d_in[9];
    const float* b2_0   = (const float*)d_in[10];
    const float* w1_r   = (const float*)d_in[11];
    const float* b1_r   = (const float*)d_in[12];
    const float* gm_r   = (const float*)d_in[13];
    const float* bt_r   = (const float*)d_in[14];
    const float* w2_r   = (const float*)d_in[15];
    const float* b2_r   = (const float*)d_in[16];
    const float* cw1    = (const float*)d_in[17];
    const float* cb1    = (const float*)d_in[18];
    const float* cgm    = (const float*)d_in[19];
    const float* cbt    = (const float*)d_in[20];
    const float* cw2    = (const float*)d_in[21];
    const float* cb2    = (const float*)d_in[22];
    float* outp = (float*)d_out;

    const int* esrc = eidx;
    const int* edst = eidx + EE;

    char* p = (char*)d_ws;
    auto alloc = [&](size_t bytes) { void* r = (void*)p; p += (bytes + 255) & ~(size_t)255; return r; };
    unsigned short* x0bf     = (unsigned short*)alloc((size_t)NN * 32 * 2);   // [NN][32] bf16
    unsigned short* y19bf    = (unsigned short*)alloc((size_t)NN * 32 * 2);
    unsigned short* hbf      = (unsigned short*)alloc((size_t)NN * HH * 2);
    unsigned*       xbf      = (unsigned*)alloc((size_t)NN * 64 * 4);
    unsigned*       ybf      = (unsigned*)alloc((size_t)NN * 64 * 4);
    int*            rp       = (int*)alloc((size_t)(NN + 1) * 4);
    int*            srcs     = (int*)alloc((size_t)EE * 4);
    int*            bincnt   = (int*)alloc((size_t)NBINS * 4);
    int*            binstart = (int*)alloc((size_t)NBINS * 4);
    int*            gptr     = (int*)alloc((BB + 1) * 4);
    short*          wt       = (short*)alloc((size_t)5 * HH * HH * 2);
    float*          part     = (float*)alloc((size_t)3125 * 256 * 4);
    float*          part2    = (float*)alloc((size_t)64 * 256 * 4);
    float*          bnscale  = (float*)alloc(HH * 4);
    float*          bnshift  = (float*)alloc(HH * 4);
    float*          psum     = (float*)alloc((size_t)BB * PCH * HH * 4);
    float*          pmax     = (float*)alloc((size_t)BB * PCH * HH * 4);
    float*          z1b      = (float*)alloc((size_t)BB * HH * 4);
    uint2*          binbuf   = (uint2*)alloc((size_t)NBINS * BCAP * 8);   // 25.7 MB

    const int NB_A = (EE + ACH - 1) / ACH;          // 782
    const int NB_AGG = (NN * 64 + 255) / 256;       // 25000
    const int NB_G32 = NN / 32;                     // 3125
    const int NB_G64 = (NN + 63) / 64;              // 1563
    const int NB_X0 = (NN * 32 + 255) / 256;        // 12500
    const int NB_WP = (5 * HH * HH + 255) / 256;    // 320

    // CSR build (LDS counting sort) + weight prep
    hipMemsetAsync(bincnt, 0, (size_t)NBINS * 4, stream);
    k_binA<<<NB_A, 256, 0, stream>>>(esrc, edst, bincnt, binbuf);
    k_binscan<<<1, 512, 0, stream>>>(bincnt, binstart, rp, batch, gptr);
    k_binB<<<NBINS, 256, 0, stream>>>(binbuf, bincnt, binstart, rp, srcs);
    k_wprep<<<NB_WP, 256, 0, stream>>>(w2_0, w1_r, w2_r, wt);

    // layer 0 (bf16 19-dim path, fp32 accumulate)
    k_buildx0<<<NB_X0, 256, 0, stream>>>(h0, coord0, x0bf);
    k_agg_small<<<NB_AGG, 256, 0, stream>>>((const uint4*)x0bf, rp, srcs, (uint4*)y19bf);
    k_gemm_small<K0, true><<<NB_G32, 256, 0, stream>>>(y19bf, w1_0, b1_0, hbf, part);
    k_statred<<<64, 256, 0, stream>>>(part, part2, NB_G32);
    k_bnfin<<<1, 128, 0, stream>>>(part2, gm_0, bt_0, bnscale, bnshift);
    k_gemm_mfma<false, true, true><<<NB_G64, 256, 0, stream>>>(hbf, wt, b2_0, bnscale, bnshift,
                                                               (unsigned short*)xbf, nullptr);

    // layers 1..2 (bf16 activations + bf16 hidden) — split agg/GEMM (best measured)
    for (int i = 0; i < 2; ++i) {
        k_agg128_bf<<<NB_AGG, 256, 0, stream>>>(xbf, rp, srcs, ybf);
        k_gemm_mfma<true, false, false><<<NB_G64, 256, 0, stream>>>((const unsigned short*)ybf,
                wt + (size_t)(1 + i) * HH * HH, b1_r + i * HH, nullptr, nullptr, hbf, part);
        k_statred<<<64, 256, 0, stream>>>(part, part2, NB_G64);
        k_bnfin<<<1, 128, 0, stream>>>(part2, gm_r + i * HH, bt_r + i * HH, bnscale, bnshift);
        k_gemm_mfma<false, true, true><<<NB_G64, 256, 0, stream>>>(hbf,
                wt + (size_t)(3 + i) * HH * HH, b2_r + i * HH, bnscale, bnshift,
                (unsigned short*)xbf, nullptr);
    }

    // pooling + classifier
    k_pool_part<<<BB * PCH, 128, 0, stream>>>((const unsigned short*)xbf, gptr, psum, pmax);
    k_pool_cls1<<<BB, 128, 0, stream>>>(psum, pmax, gptr, g0, cw1, cb1, z1b);
    k_cls2<<<1, 128, 0, stream>>>(z1b, cgm, cbt, cw2, cb2, outp);
}